// Round 6
// baseline (323.331 us; speedup 1.0000x reference)
//
#include <hip/hip_runtime.h>
#include <stdint.h>

#define B_   2
#define S_   2048
#define D_   2048
#define QH_  32
#define KVH_ 8
#define HD_  64

typedef short  short8  __attribute__((ext_vector_type(8)));
typedef float  floatx4 __attribute__((ext_vector_type(4)));

__device__ __forceinline__ ushort f2b(float f) {
  union { float f; uint32_t u; } c; c.f = f;
  uint32_t u = c.u;
  return (ushort)((u + 0x7FFFu + ((u >> 16) & 1u)) >> 16);
}

__device__ __forceinline__ uint32_t fbits(float f) {
  union { float f; uint32_t u; } c; c.f = f;
  return c.u;
}

__device__ __forceinline__ short8 mk8(uint32_t a, uint32_t b, uint32_t c, uint32_t d) {
  union { uint4 u; short8 s; } v; v.u = (uint4){a, b, c, d}; return v.s;
}

// packed bf16 convert: lo = bf16(a), hi = bf16(b).
__device__ __forceinline__ uint32_t cvtpk(float a, float b) {
  uint32_t r;
  asm("v_cvt_pk_bf16_f32 %0, %1, %2" : "=v"(r) : "v"(a), "v"(b));
  return r;
}

// async global->LDS DMA, 16B per lane. LDS dest = wave-uniform base + lane*16.
__device__ __forceinline__ void dma16(const void* g, void* l) {
  __builtin_amdgcn_global_load_lds(
      (const __attribute__((address_space(1))) uint32_t*)(uintptr_t)g,
      (__attribute__((address_space(3))) uint32_t*)(uintptr_t)l, 16, 0, 0);
}

#define QSCALE 0.18033688f   // 1/sqrt(64) * log2(e)

// ---------------- elementwise converts ----------------

__global__ __launch_bounds__(256) void conv_x_kernel(const float* __restrict__ X,
                                                     ushort* __restrict__ Xb) {
  size_t i = ((size_t)blockIdx.x * 256 + threadIdx.x) * 4;
  float4 v = *(const float4*)(X + i);
  ushort4 o;
  o.x = f2b(v.x); o.y = f2b(v.y); o.z = f2b(v.z); o.w = f2b(v.w);
  *(ushort4*)(Xb + i) = o;
}

// Batched transpose+convert: z selects {Wq, Wk, Wv, Wo}. W [K=2048][N] -> Wt [N][K] bf16.
__global__ void tconv_all_kernel(const float* __restrict__ Wq, const float* __restrict__ Wk,
                                 const float* __restrict__ Wv, const float* __restrict__ Wo,
                                 ushort* __restrict__ wqkv, ushort* __restrict__ wo) {
  __shared__ float tile[32][33];
  int z = blockIdx.z;
  const float* W; ushort* Wt; int N;
  if (z == 0)      { W = Wq; Wt = wqkv;                        N = 2048; }
  else if (z == 1) { W = Wk; Wt = wqkv + (size_t)2048 * 2048;  N = 512;  }
  else if (z == 2) { W = Wv; Wt = wqkv + (size_t)2560 * 2048;  N = 512;  }
  else             { W = Wo; Wt = wo;                          N = 2048; }
  int bx = blockIdx.x, by = blockIdx.y;
  if (bx * 32 >= N) return;
  int tx = threadIdx.x, ty = threadIdx.y;
#pragma unroll
  for (int i = 0; i < 32; i += 8)
    tile[ty + i][tx] = W[(size_t)(by * 32 + ty + i) * N + bx * 32 + tx];
  __syncthreads();
#pragma unroll
  for (int i = 0; i < 32; i += 8)
    Wt[(size_t)(bx * 32 + ty + i) * 2048 + by * 32 + tx] = f2b(tile[tx][ty + i]);
}

// ---------------- fused QKV GEMM (2-phase 128x128) + bias + RoPE ----------
// Proven main loop (r1/r3: 76.5-77.2 us). Epilogue fuses bias (direct
// bq/bk/bv) and V->Vt (vpack) as verified in r5.
// Q/K head dim stored PERMUTED: d' = l16*4 + ni  (true d = ni*16 + l16,
// i.e. d' = (d&15)*4 + (d>>4)); QK^T invariant since Q,K share it.
// V path: acc(mi,ni,r) = V[s][true d = ni*16+l16], head h=(bn-20)*2+(wave&1);
//   Vt row dt = ni*16+l16; pos-perm over s&63 = (mi&2)*16+quad*8+(mi&1)*4+r
//   (r contiguous -> one ushort4 store).

__global__ __launch_bounds__(256) void gemm_qkv_kernel(
    const ushort* __restrict__ A, const ushort* __restrict__ Bt,
    const float* __restrict__ bq, const float* __restrict__ bk,
    const float* __restrict__ bv, const float2* __restrict__ F2,
    ushort* __restrict__ qb, ushort* __restrict__ kb, ushort* __restrict__ vt) {
  const int K = 2048;
  __shared__ ushort sA[2][128 * 32];
  __shared__ ushort sB[2][128 * 32];
  const int tid  = threadIdx.x;
  const int bm   = blockIdx.y, bn = blockIdx.x;
  const int wave = tid >> 6, lane = tid & 63;
  const int quad = lane >> 4, l16 = lane & 15;
  const int wm   = (wave >> 1) * 64, wn = (wave & 1) * 64;

  const ushort* Ab = A  + (size_t)(bm * 128) * K;
  const ushort* Bb = Bt + (size_t)(bn * 128) * K;

  const int gr = lane >> 2;
  const int gu = (lane & 3) * 8;

  floatx4 acc[4][4];
#pragma unroll
  for (int i = 0; i < 4; i++)
#pragma unroll
    for (int j = 0; j < 4; j++) acc[i][j] = (floatx4){0.f, 0.f, 0.f, 0.f};

#pragma unroll
  for (int j = 0; j < 2; j++) {
    int row = j * 64 + wave * 16 + gr;
    dma16(Ab + (size_t)row * K + gu, &sA[0][j * 2048 + wave * 512]);
    dma16(Bb + (size_t)row * K + gu, &sB[0][j * 2048 + wave * 512]);
  }

  int cur = 0;
  for (int k0 = 0; k0 < K; k0 += 32) {
    __syncthreads();
    if (k0 + 32 < K) {
      int nxt = cur ^ 1;
#pragma unroll
      for (int j = 0; j < 2; j++) {
        int row = j * 64 + wave * 16 + gr;
        dma16(Ab + (size_t)row * K + k0 + 32 + gu, &sA[nxt][j * 2048 + wave * 512]);
        dma16(Bb + (size_t)row * K + k0 + 32 + gu, &sB[nxt][j * 2048 + wave * 512]);
      }
    }
    short8 af[4], bf[4];
#pragma unroll
    for (int mi = 0; mi < 4; mi++)
      af[mi] = *(const short8*)&sA[cur][(wm + mi * 16 + l16) * 32 + quad * 8];
#pragma unroll
    for (int ni = 0; ni < 4; ni++)
      bf[ni] = *(const short8*)&sB[cur][(wn + ni * 16 + l16) * 32 + quad * 8];
#pragma unroll
    for (int mi = 0; mi < 4; mi++)
#pragma unroll
      for (int ni = 0; ni < 4; ni++)
        acc[mi][ni] = __builtin_amdgcn_mfma_f32_16x16x32_bf16(
            af[mi], bf[ni], acc[mi][ni], 0, 0, 0);
    cur ^= 1;
  }

  // ---- fused epilogue ----
  const int isQ = (bn < 16);
  const int isV = (bn >= 20);
  const int hh  = wn >> 6;
  const float sySign = (l16 & 1) ? 1.f : -1.f;

  const float* bsrc = isQ ? bq : (isV ? bv : bk);
  const int    boff = isQ ? 0  : (isV ? 2560 : 2048);

  float bvv[4];
#pragma unroll
  for (int ni = 0; ni < 4; ni++)
    bvv[ni] = bsrc[bn * 128 + wn + ni * 16 + l16 - boff];

  if (!isV) {
    ushort* dst = isQ ? qb : kb;
    const int NH    = isQ ? QH_ : KVH_;
    const int hbase = isQ ? (bn * 2 + hh) : ((bn - 16) * 2 + hh);
#pragma unroll
    for (int mi = 0; mi < 4; mi++) {
#pragma unroll
      for (int r = 0; r < 4; r++) {
        int row = bm * 128 + wm + mi * 16 + quad * 4 + r;
        int s = row & 2047, bb = row >> 11;
        size_t base = (((size_t)bb * NH + hbase) * S_ + s) * HD_ + l16 * 4;
        float o[4];
#pragma unroll
        for (int ni = 0; ni < 4; ni++) {
          float xv = acc[mi][ni][r] + bvv[ni];
          float2 cs = F2[s * 32 + ni * 8 + (l16 >> 1)];
          float pp = __shfl_xor(xv, 1);
          float oo = fmaf(pp * sySign, cs.y, xv * cs.x);
          if (isQ) oo *= QSCALE;
          o[ni] = oo;
        }
        ushort4 pk;
        pk.x = f2b(o[0]); pk.y = f2b(o[1]); pk.z = f2b(o[2]); pk.w = f2b(o[3]);
        *(ushort4*)&dst[base] = pk;
      }
    }
  } else {
    // V: write directly into Vt [bb*8+h][64 dt][2048 pos-perm] (vpack fused).
    const int h = (bn - 20) * 2 + hh;
#pragma unroll
    for (int mi = 0; mi < 4; mi++) {
      int row0 = bm * 128 + wm + mi * 16 + quad * 4;
      int bb   = row0 >> 11;
      int posb = ((row0 & 2047) & ~63) + (mi & 2) * 16 + quad * 8 + (mi & 1) * 4;
#pragma unroll
      for (int ni = 0; ni < 4; ni++) {
        int dt = ni * 16 + l16;
        ushort4 st;
        st.x = f2b(acc[mi][ni][0] + bvv[ni]);
        st.y = f2b(acc[mi][ni][1] + bvv[ni]);
        st.z = f2b(acc[mi][ni][2] + bvv[ni]);
        st.w = f2b(acc[mi][ni][3] + bvv[ni]);
        *(ushort4*)&vt[(((size_t)bb * 8 + h) * 64 + dt) * (size_t)S_ + posb] = st;
      }
    }
  }
}

// ---------------- GEMM: C[M][N] = A @ Bt^T + bias (fp32 out) ----------------

__global__ __launch_bounds__(256) void gemm_bt_kernel(
    const ushort* __restrict__ A, const ushort* __restrict__ Bt,
    const float* __restrict__ bias, float* __restrict__ C,
    int M, int N, int K) {
  __shared__ ushort sA[2][128 * 32];
  __shared__ ushort sB[2][128 * 32];
  const int tid  = threadIdx.x;
  const int bm   = blockIdx.y, bn = blockIdx.x;
  const int wave = tid >> 6, lane = tid & 63;
  const int quad = lane >> 4, l16 = lane & 15;
  const int wm   = (wave >> 1) * 64, wn = (wave & 1) * 64;

  const ushort* Ab = A  + (size_t)(bm * 128) * K;
  const ushort* Bb = Bt + (size_t)(bn * 128) * K;

  const int gr = lane >> 2;
  const int gu = (lane & 3) * 8;

  floatx4 acc[4][4];
#pragma unroll
  for (int i = 0; i < 4; i++)
#pragma unroll
    for (int j = 0; j < 4; j++) acc[i][j] = (floatx4){0.f, 0.f, 0.f, 0.f};

#pragma unroll
  for (int j = 0; j < 2; j++) {
    int row = j * 64 + wave * 16 + gr;
    dma16(Ab + (size_t)row * K + gu, &sA[0][j * 2048 + wave * 512]);
    dma16(Bb + (size_t)row * K + gu, &sB[0][j * 2048 + wave * 512]);
  }

  int cur = 0;
  for (int k0 = 0; k0 < K; k0 += 32) {
    __syncthreads();
    if (k0 + 32 < K) {
      int nxt = cur ^ 1;
#pragma unroll
      for (int j = 0; j < 2; j++) {
        int row = j * 64 + wave * 16 + gr;
        dma16(Ab + (size_t)row * K + k0 + 32 + gu, &sA[nxt][j * 2048 + wave * 512]);
        dma16(Bb + (size_t)row * K + k0 + 32 + gu, &sB[nxt][j * 2048 + wave * 512]);
      }
    }
    short8 af[4], bf[4];
#pragma unroll
    for (int mi = 0; mi < 4; mi++)
      af[mi] = *(const short8*)&sA[cur][(wm + mi * 16 + l16) * 32 + quad * 8];
#pragma unroll
    for (int ni = 0; ni < 4; ni++)
      bf[ni] = *(const short8*)&sB[cur][(wn + ni * 16 + l16) * 32 + quad * 8];
#pragma unroll
    for (int mi = 0; mi < 4; mi++)
#pragma unroll
      for (int ni = 0; ni < 4; ni++)
        acc[mi][ni] = __builtin_amdgcn_mfma_f32_16x16x32_bf16(
            af[mi], bf[ni], acc[mi][ni], 0, 0, 0);
    cur ^= 1;
  }

#pragma unroll
  for (int mi = 0; mi < 4; mi++) {
#pragma unroll
    for (int ni = 0; ni < 4; ni++) {
      int col  = bn * 128 + wn + ni * 16 + l16;
      float bv = bias[col];
#pragma unroll
      for (int r = 0; r < 4; r++) {
        int row = bm * 128 + wm + mi * 16 + quad * 4 + r;
        C[(size_t)row * N + col] = acc[mi][ni][r] + bv;
      }
    }
  }
}

// ---------------- Flash attention (register P, no LDS round-trip) ----------
// grid flat 512 blocks, block 512 (8 waves), 2 blocks/CU (4 waves/SIMD).
// Block-id remap clusters all 32 blocks sharing one (b,kvh)'s K/V onto one
// XCD: id = kvh + 8*qt + 64*g + 256*b.
// Inner loop REORDERED (r6): all 16 QK MFMAs -> all exp2/pack -> all 16 PV
// MFMAs per kv-tile, to lengthen MFMA issue bursts and overlap exp2 with
// in-flight QK MFMAs. No sync changes.

__global__ __launch_bounds__(512, 4) void attn_kernel(
    const ushort* __restrict__ Q, const ushort* __restrict__ K,
    const ushort* __restrict__ Vt, ushort* __restrict__ O) {
  const int id  = blockIdx.x + 8 * (blockIdx.y + 32 * blockIdx.z);
  const int kvh = id & 7;
  const int qt  = (id >> 3) & 7;
  const int qh  = kvh * 4 + ((id >> 6) & 3);
  const int b   = id >> 8;
  const int tid = threadIdx.x;
  const int wave = tid >> 6, lane = tid & 63;
  const int quad = lane >> 4, l16 = lane & 15;

  __shared__ ushort kBuf[2][64 * 64];   // 16 KB
  __shared__ ushort vBuf[2][64 * 64];   // 16 KB

  const ushort* Qh = Q  + ((size_t)(b * QH_ + qh)) * S_ * HD_;
  const ushort* Kh = K  + ((size_t)(b * KVH_ + kvh)) * S_ * HD_;
  const ushort* Vh = Vt + ((size_t)(b * KVH_ + kvh)) * HD_ * S_;

  const int dr = lane >> 3;
  const int du = (lane & 7) ^ (dr & 7);
  const size_t kLaneOff = (size_t)(wave * 8 + dr) * 64 + du * 8;
  const size_t vLaneOff = (size_t)(wave * 8 + dr) * S_ + du * 8;
  const int swz = l16 & 7;

  const int q0 = qt * 256 + wave * 32;
  short8 aq[2][2];
#pragma unroll
  for (int m = 0; m < 2; m++)
#pragma unroll
    for (int s2 = 0; s2 < 2; s2++)
      aq[m][s2] = *(const short8*)(Qh + (size_t)(q0 + m * 16 + l16) * HD_ + s2 * 32 + quad * 8);

  floatx4 oacc[2][4];
#pragma unroll
  for (int m = 0; m < 2; m++)
#pragma unroll
    for (int t = 0; t < 4; t++) oacc[m][t] = (floatx4){0.f, 0.f, 0.f, 0.f};
  float ls[2] = {0.f, 0.f};

  dma16(Kh + kLaneOff, &kBuf[0][wave * 512]);
  dma16(Vh + vLaneOff, &vBuf[0][wave * 512]);

  int cur = 0;
  for (int kv0 = 0; kv0 < S_; kv0 += 64) {
    __syncthreads();
    if (kv0 + 64 < S_) {
      int nxt = cur ^ 1;
      dma16(Kh + (size_t)(kv0 + 64) * 64 + kLaneOff, &kBuf[nxt][wave * 512]);
      dma16(Vh + (size_t)(kv0 + 64) + vLaneOff,      &vBuf[nxt][wave * 512]);
    }

    // ---- QK: all 16 MFMAs ----
    floatx4 sc[2][2][2];   // [u][cc][m]
    __builtin_amdgcn_s_setprio(1);
#pragma unroll
    for (int u = 0; u < 2; u++) {
#pragma unroll
      for (int cc = 0; cc < 2; cc++) {
        const int c = u * 2 + cc;
        short8 kf0 = *(const short8*)&kBuf[cur][(c * 16 + l16) * 64 + ((quad ^ swz) * 8)];
        short8 kf1 = *(const short8*)&kBuf[cur][(c * 16 + l16) * 64 + (((4 + quad) ^ swz) * 8)];
#pragma unroll
        for (int m = 0; m < 2; m++) {
          floatx4 s0 = (floatx4){0.f, 0.f, 0.f, 0.f};
          s0 = __builtin_amdgcn_mfma_f32_16x16x32_bf16(kf0, aq[m][0], s0, 0, 0, 0);
          sc[u][cc][m] = __builtin_amdgcn_mfma_f32_16x16x32_bf16(kf1, aq[m][1], s0, 0, 0, 0);
        }
      }
    }
    __builtin_amdgcn_s_setprio(0);

    // ---- softmax numerators: exp2 + pack ----
    uint32_t pk[2][2][4];  // [u][m][word]
#pragma unroll
    for (int u = 0; u < 2; u++)
#pragma unroll
      for (int cc = 0; cc < 2; cc++)
#pragma unroll
        for (int m = 0; m < 2; m++) {
          float p0 = __builtin_amdgcn_exp2f(sc[u][cc][m][0]);
          float p1 = __builtin_amdgcn_exp2f(sc[u][cc][m][1]);
          float p2 = __builtin_amdgcn_exp2f(sc[u][cc][m][2]);
          float p3 = __builtin_amdgcn_exp2f(sc[u][cc][m][3]);
          ls[m] += (p0 + p1) + (p2 + p3);
          pk[u][m][cc * 2 + 0] = cvtpk(p0, p1);
          pk[u][m][cc * 2 + 1] = cvtpk(p2, p3);
        }

    // ---- PV: all 16 MFMAs ----
#pragma unroll
    for (int u = 0; u < 2; u++) {
      short8 ap[2];
#pragma unroll
      for (int m = 0; m < 2; m++)
        ap[m] = mk8(pk[u][m][0], pk[u][m][1], pk[u][m][2], pk[u][m][3]);
      __builtin_amdgcn_s_setprio(1);
#pragma unroll
      for (int t = 0; t < 4; t++) {
        const int row = (t * 16 + l16) * 64;
        short8 vf = *(const short8*)&vBuf[cur][row + (((u * 4 + quad) ^ swz) * 8)];
#pragma unroll
        for (int m = 0; m < 2; m++)
          oacc[m][t] = __builtin_amdgcn_mfma_f32_16x16x32_bf16(ap[m], vf, oacc[m][t], 0, 0, 0);
      }
      __builtin_amdgcn_s_setprio(0);
    }
    cur ^= 1;
  }

#pragma unroll
  for (int m = 0; m < 2; m++) {
    ls[m] += __shfl_xor(ls[m], 16);
    ls[m] += __shfl_xor(ls[m], 32);
  }
#pragma unroll
  for (int m = 0; m < 2; m++) {
#pragma unroll
    for (int r = 0; r < 4; r++) {
      float l = __shfl(ls[m], (lane & 48) | (quad * 4 + r));
      float inv = 1.0f / l;
      int srow = q0 + m * 16 + quad * 4 + r;
      size_t base = ((size_t)b * S_ + srow) * (QH_ * HD_) + (size_t)qh * HD_;
#pragma unroll
      for (int t = 0; t < 4; t++)
        O[base + t * 16 + l16] = f2b(oacc[m][t][r] * inv);
    }
  }
}

// ---------------- launch ----------------

extern "C" void kernel_launch(void* const* d_in, const int* in_sizes, int n_in,
                              void* d_out, int out_size, void* d_ws, size_t ws_size,
                              hipStream_t stream) {
  const float* x  = (const float*)d_in[0];
  const float* fr = (const float*)d_in[1];
  const float* Wq = (const float*)d_in[2];
  const float* bq = (const float*)d_in[3];
  const float* Wk = (const float*)d_in[4];
  const float* bk = (const float*)d_in[5];
  const float* Wv = (const float*)d_in[6];
  const float* bv = (const float*)d_in[7];
  const float* Wo = (const float*)d_in[8];
  const float* bo = (const float*)d_in[9];
  float* out = (float*)d_out;
  char* ws = (char*)d_ws;

  ushort* xb    = (ushort*)(ws + 0);           // 16,777,216  x bf16 (reused as Ob)
  ushort* wqkv  = (ushort*)(ws + 16777216);    // 12,582,912
  ushort* wo    = (ushort*)(ws + 29360128);    //  8,388,608
  ushort* qb    = (ushort*)(ws + 37761024);    // 16,777,216  Q roped bf16 (perm d)
  ushort* kb    = (ushort*)(ws + 54538240);    //  4,194,304  K roped bf16 (perm d)
  ushort* vt    = (ushort*)(ws + 62926848);    //  4,194,304  V [d][s-perm] true-d
  ushort* ob    = xb;                          // alias: xb dead after gemm1

  conv_x_kernel<<<8192, 256, 0, stream>>>(x, xb);
  tconv_all_kernel<<<dim3(64, 64, 4), dim3(32, 8), 0, stream>>>(Wq, Wk, Wv, Wo, wqkv, wo);

  gemm_qkv_kernel<<<dim3(3072 / 128, 4096 / 128), 256, 0, stream>>>(
      xb, wqkv, bq, bk, bv, (const float2*)fr, qb, kb, vt);

  attn_kernel<<<dim3(8, 32, 2), 512, 0, stream>>>(qb, kb, vt, ob);

  gemm_bt_kernel<<<dim3(2048 / 128, 4096 / 128), 256, 0, stream>>>(
      ob, wo, bo, out, 4096, 2048, 2048);
}